// Round 1
// baseline (3757.233 us; speedup 1.0000x reference)
//
#include <hip/hip_runtime.h>
#include <math.h>

// IntegralTransform: per-edge MLP(38->64->64->32, exact gelu) * f_y[j] * w[j],
// segment-summed over K=32 neighbors per point.
// Round 1: fp32 baseline, 1 thread = 1 edge, weights via scalar loads
// (uniform indices), h1/h2 in registers (full unroll), LDS transpose-reduce.

#define BLOCK 256

__device__ __forceinline__ float gelu_exact(float x) {
    return 0.5f * x * (1.0f + erff(x * 0.7071067811865475f));
}

__global__ __launch_bounds__(BLOCK, 2) void it_kernel(
    const float* __restrict__ y, const float* __restrict__ fy,
    const float* __restrict__ wts,
    const float* __restrict__ W1, const float* __restrict__ b1,
    const float* __restrict__ W2, const float* __restrict__ b2,
    const float* __restrict__ W3, const float* __restrict__ b3,
    const int* __restrict__ nbr,
    float* __restrict__ out, int E)
{
    __shared__ float red[BLOCK * 33];

    const int e = blockIdx.x * BLOCK + threadIdx.x;
    const bool valid = (e < E);

    int j = 0;
    float w = 0.f;
    float agg[38];
    #pragma unroll
    for (int k = 0; k < 38; ++k) agg[k] = 0.f;

    if (valid) {
        j = nbr[e];
        const int i = e >> 5;  // row_splits are uniform i*32
        agg[0] = y[3*j+0]; agg[1] = y[3*j+1]; agg[2] = y[3*j+2];
        agg[3] = y[3*i+0]; agg[4] = y[3*i+1]; agg[5] = y[3*i+2];
        const float4* fp = (const float4*)(fy + 32*j);
        #pragma unroll
        for (int q = 0; q < 8; ++q) {
            float4 v = fp[q];
            agg[6+4*q+0] = v.x; agg[6+4*q+1] = v.y;
            agg[6+4*q+2] = v.z; agg[6+4*q+3] = v.w;
        }
        w = wts[j];
    }

    // ---- layer 1: h1 = gelu(agg @ W1 + b1), W1 is [38,64] row-major ----
    float h1[64];
    #pragma unroll
    for (int l = 0; l < 64; ++l) h1[l] = b1[l];
    #pragma unroll
    for (int k = 0; k < 38; ++k) {
        const float a = agg[k];
        const float* wr = W1 + k * 64;
        #pragma unroll
        for (int l = 0; l < 64; ++l) h1[l] = fmaf(a, wr[l], h1[l]);
    }
    #pragma unroll
    for (int l = 0; l < 64; ++l) h1[l] = gelu_exact(h1[l]);

    // ---- layer 2: h2 = gelu(h1 @ W2 + b2), W2 is [64,64] ----
    float h2[64];
    #pragma unroll
    for (int l = 0; l < 64; ++l) h2[l] = b2[l];
    #pragma unroll
    for (int k = 0; k < 64; ++k) {
        const float a = h1[k];
        const float* wr = W2 + k * 64;
        #pragma unroll
        for (int l = 0; l < 64; ++l) h2[l] = fmaf(a, wr[l], h2[l]);
    }
    #pragma unroll
    for (int l = 0; l < 64; ++l) h2[l] = gelu_exact(h2[l]);

    // ---- layer 3: o = h2 @ W3 + b3, W3 is [64,32] ----
    float o[32];
    #pragma unroll
    for (int c = 0; c < 32; ++c) o[c] = b3[c];
    #pragma unroll
    for (int l = 0; l < 64; ++l) {
        const float a = h2[l];
        const float* wr = W3 + l * 32;
        #pragma unroll
        for (int c = 0; c < 32; ++c) o[c] = fmaf(a, wr[c], o[c]);
    }

    // ---- o *= f_y[j] * weights[j] (w==0 for invalid lanes -> 0) ----
    {
        const float4* fp = (const float4*)(fy + 32*j);
        #pragma unroll
        for (int q = 0; q < 8; ++q) {
            float4 v = fp[q];
            o[4*q+0] *= v.x * w; o[4*q+1] *= v.y * w;
            o[4*q+2] *= v.z * w; o[4*q+3] *= v.w * w;
        }
    }

    // ---- segment sum: 32 consecutive threads = one point ----
    #pragma unroll
    for (int c = 0; c < 32; ++c) red[threadIdx.x * 33 + c] = o[c];
    __syncthreads();

    const int p = threadIdx.x >> 5;   // 8 points per block
    const int c = threadIdx.x & 31;
    float s = 0.f;
    #pragma unroll
    for (int t = 0; t < 32; ++t) s += red[(p * 32 + t) * 33 + c];
    const int point = blockIdx.x * 8 + p;
    if (point < (E >> 5)) out[point * 32 + c] = s;
}

extern "C" void kernel_launch(void* const* d_in, const int* in_sizes, int n_in,
                              void* d_out, int out_size, void* d_ws, size_t ws_size,
                              hipStream_t stream) {
    const float* y  = (const float*)d_in[0];
    const float* fy = (const float*)d_in[1];
    const float* wt = (const float*)d_in[2];
    const float* W1 = (const float*)d_in[3];
    const float* b1 = (const float*)d_in[4];
    const float* W2 = (const float*)d_in[5];
    const float* b2 = (const float*)d_in[6];
    const float* W3 = (const float*)d_in[7];
    const float* b3 = (const float*)d_in[8];
    const int* nbr  = (const int*)d_in[9];
    const int E = in_sizes[9];
    float* out = (float*)d_out;

    const int blocks = (E + BLOCK - 1) / BLOCK;
    hipLaunchKernelGGL(it_kernel, dim3(blocks), dim3(BLOCK), 0, stream,
                       y, fy, wt, W1, b1, W2, b2, W3, b3, nbr, out, E);
}

// Round 2
// 267.329 us; speedup vs baseline: 14.0547x; 14.0547x over previous
//
#include <hip/hip_runtime.h>
#include <math.h>

// IntegralTransform via bf16 MFMA (16x16x32), one wave = one point (32 edges).
// Weights as register B-fragments (loaded once, bf16). Activations round-trip
// per-wave LDS buffers (stride 72 bf16 = 144B). No __syncthreads anywhere:
// buffers are per-wave and same-wave DS ops are processed in order.
// Segment-sum = in-register row reduction of MFMA C-layout + shfl_xor(16,32).

typedef __attribute__((ext_vector_type(8))) short short8;
typedef __attribute__((ext_vector_type(4))) float floatx4;

__device__ __forceinline__ unsigned short bf16rne(float f) {
    unsigned int u = __float_as_uint(f);
    u += 0x7fffu + ((u >> 16) & 1u);
    return (unsigned short)(u >> 16);
}
__device__ __forceinline__ unsigned int bfpk(float a, float b) {
    return (unsigned int)bf16rne(a) | ((unsigned int)bf16rne(b) << 16);
}
// tanh-form gelu; |err| vs exact-erf gelu ~3e-4, threshold is 3.1e-1.
__device__ __forceinline__ float gelu_fast(float x) {
    float u = 0.7978845608f * fmaf(0.044715f * x, x * x, x);
    float e = __expf(2.0f * u);                       // exp(2u); inf-safe
    float t = 1.0f - 2.0f * __builtin_amdgcn_rcpf(e + 1.0f);  // tanh(u)
    return 0.5f * x * (1.0f + t);
}

#define MFMA16(a, b, c) __builtin_amdgcn_mfma_f32_16x16x32_bf16(a, b, c, 0, 0, 0)

__global__ __launch_bounds__(256, 2) void it_mfma(
    const float* __restrict__ y, const float* __restrict__ fy,
    const float* __restrict__ wts,
    const float* __restrict__ W1, const float* __restrict__ b1,
    const float* __restrict__ W2, const float* __restrict__ b2,
    const float* __restrict__ W3, const float* __restrict__ b3,
    const int* __restrict__ nbr,
    float* __restrict__ out, int npts)
{
    __shared__ unsigned short lds[4][2][32][72];   // [wave][buf][row][col] 36864 B

    const int lane = threadIdx.x & 63;
    const int wv   = threadIdx.x >> 6;
    const int p    = blockIdx.x * 4 + wv;          // one point per wave
    if (p >= npts) return;
    const int quad = lane >> 4;
    const int c16  = lane & 15;

    // ---- weight fragments (bf16, B-layout: k = 32*kb + 8*quad + j, n = 16*nb + c16)
    // k-permutation: k'<32 -> W1 row 6+k' (fy block); 32..37 -> rows 0..5 (y[j],y[i]); else 0
    short8 w1f[2][4], w2f[2][4], w3f[2][2];
    #pragma unroll
    for (int kb = 0; kb < 2; ++kb)
        #pragma unroll
        for (int nb = 0; nb < 4; ++nb)
            #pragma unroll
            for (int j = 0; j < 8; ++j) {
                int kp = kb * 32 + quad * 8 + j;
                int n  = nb * 16 + c16;
                int r  = (kp < 32) ? (6 + kp) : (kp < 38 ? kp - 32 : -1);
                float v = (r >= 0) ? W1[r * 64 + n] : 0.f;
                w1f[kb][nb][j] = (short)bf16rne(v);
            }
    #pragma unroll
    for (int kb = 0; kb < 2; ++kb)
        #pragma unroll
        for (int nb = 0; nb < 4; ++nb)
            #pragma unroll
            for (int j = 0; j < 8; ++j) {
                int k = kb * 32 + quad * 8 + j;
                w2f[kb][nb][j] = (short)bf16rne(W2[k * 64 + nb * 16 + c16]);
            }
    #pragma unroll
    for (int kb = 0; kb < 2; ++kb)
        #pragma unroll
        for (int nb = 0; nb < 2; ++nb)
            #pragma unroll
            for (int j = 0; j < 8; ++j) {
                int k = kb * 32 + quad * 8 + j;
                w3f[kb][nb][j] = (short)bf16rne(W3[k * 32 + nb * 16 + c16]);
            }
    float b1v[4], b2v[4], b3v[2];
    #pragma unroll
    for (int nb = 0; nb < 4; ++nb) { b1v[nb] = b1[nb * 16 + c16]; b2v[nb] = b2[nb * 16 + c16]; }
    b3v[0] = b3[c16]; b3v[1] = b3[16 + c16];

    unsigned short (*bufA)[72] = lds[wv][0];
    unsigned short (*bufB)[72] = lds[wv][1];

    // ---- stage agg tile [32 rows][64 cols] (bf16): 2 lanes per edge-row ----
    {
        const int row = lane >> 1;
        const int e   = p * 32 + row;
        const int j   = nbr[e];
        if ((lane & 1) == 0) {
            // cols 0..31 = fy[j][0..31]
            const float4* fp = (const float4*)(fy + (long)j * 32);
            unsigned int pk[16];
            #pragma unroll
            for (int q = 0; q < 8; ++q) {
                float4 v4 = fp[q];
                pk[2 * q]     = bfpk(v4.x, v4.y);
                pk[2 * q + 1] = bfpk(v4.z, v4.w);
            }
            uint4* dst = (uint4*)&bufA[row][0];
            #pragma unroll
            for (int q = 0; q < 4; ++q)
                dst[q] = make_uint4(pk[4 * q], pk[4 * q + 1], pk[4 * q + 2], pk[4 * q + 3]);
        } else {
            // cols 32..37 = y[j](3), y[p](3); 38..63 = 0
            float yj0 = y[3 * j], yj1 = y[3 * j + 1], yj2 = y[3 * j + 2];
            float yi0 = y[3 * p], yi1 = y[3 * p + 1], yi2 = y[3 * p + 2];
            uint4* dst = (uint4*)&bufA[row][32];
            dst[0] = make_uint4(bfpk(yj0, yj1), bfpk(yj2, yi0), bfpk(yi1, yi2), 0u);
            dst[1] = make_uint4(0u, 0u, 0u, 0u);
            dst[2] = make_uint4(0u, 0u, 0u, 0u);
            dst[3] = make_uint4(0u, 0u, 0u, 0u);
        }
    }

    const floatx4 fz = {0.f, 0.f, 0.f, 0.f};
    float colsum0 = 0.f, colsum1 = 0.f;

    #pragma unroll
    for (int t = 0; t < 2; ++t) {
        const int arow = t * 16 + c16;               // A-frag row for this lane
        // ---- layer 1 ----
        short8 a0 = *(const short8*)&bufA[arow][quad * 8];
        short8 a1 = *(const short8*)&bufA[arow][32 + quad * 8];
        floatx4 acc[4];
        #pragma unroll
        for (int nb = 0; nb < 4; ++nb) {
            acc[nb] = MFMA16(a0, w1f[0][nb], fz);
            acc[nb] = MFMA16(a1, w1f[1][nb], acc[nb]);
        }
        #pragma unroll
        for (int nb = 0; nb < 4; ++nb)
            #pragma unroll
            for (int r = 0; r < 4; ++r) {
                float g = gelu_fast(acc[nb][r] + b1v[nb]);
                bufB[t * 16 + quad * 4 + r][nb * 16 + c16] = bf16rne(g);
            }
        // ---- layer 2 ----
        short8 h0 = *(const short8*)&bufB[arow][quad * 8];
        short8 h1 = *(const short8*)&bufB[arow][32 + quad * 8];
        #pragma unroll
        for (int nb = 0; nb < 4; ++nb) {
            acc[nb] = MFMA16(h0, w2f[0][nb], fz);
            acc[nb] = MFMA16(h1, w2f[1][nb], acc[nb]);
        }
        #pragma unroll
        for (int nb = 0; nb < 4; ++nb)
            #pragma unroll
            for (int r = 0; r < 4; ++r) {
                float g = gelu_fast(acc[nb][r] + b2v[nb]);
                bufA[t * 16 + quad * 4 + r][nb * 16 + c16] = bf16rne(g);  // overwrite consumed agg rows
            }
        // ---- layer 3 ----
        short8 g0 = *(const short8*)&bufA[arow][quad * 8];
        short8 g1 = *(const short8*)&bufA[arow][32 + quad * 8];
        floatx4 o[2];
        #pragma unroll
        for (int nb = 0; nb < 2; ++nb) {
            o[nb] = MFMA16(g0, w3f[0][nb], fz);
            o[nb] = MFMA16(g1, w3f[1][nb], o[nb]);
        }
        // ---- epilogue: (o + b3) * fy[j] * w[j], accumulate rows ----
        #pragma unroll
        for (int r = 0; r < 4; ++r) {
            int row = t * 16 + quad * 4 + r;
            int jj  = nbr[p * 32 + row];
            float wvv = wts[jj];
            float sc0 = fy[(long)jj * 32 + c16] * wvv;
            float sc1 = fy[(long)jj * 32 + 16 + c16] * wvv;
            colsum0 += (o[0][r] + b3v[0]) * sc0;
            colsum1 += (o[1][r] + b3v[1]) * sc1;
        }
    }

    // reduce across quads (rows) and store one point [32 ch]
    colsum0 += __shfl_xor(colsum0, 16, 64);
    colsum0 += __shfl_xor(colsum0, 32, 64);
    colsum1 += __shfl_xor(colsum1, 16, 64);
    colsum1 += __shfl_xor(colsum1, 32, 64);
    if (lane < 32)
        out[p * 32 + lane] = (lane < 16) ? colsum0 : colsum1;
}

extern "C" void kernel_launch(void* const* d_in, const int* in_sizes, int n_in,
                              void* d_out, int out_size, void* d_ws, size_t ws_size,
                              hipStream_t stream) {
    const float* y  = (const float*)d_in[0];
    const float* fy = (const float*)d_in[1];
    const float* wt = (const float*)d_in[2];
    const float* W1 = (const float*)d_in[3];
    const float* b1 = (const float*)d_in[4];
    const float* W2 = (const float*)d_in[5];
    const float* b2 = (const float*)d_in[6];
    const float* W3 = (const float*)d_in[7];
    const float* b3 = (const float*)d_in[8];
    const int* nbr  = (const int*)d_in[9];
    const int E = in_sizes[9];
    const int npts = E >> 5;              // K = 32 fixed
    float* out = (float*)d_out;

    const int blocks = (npts + 3) / 4;    // 4 waves (points) per block
    hipLaunchKernelGGL(it_mfma, dim3(blocks), dim3(256), 0, stream,
                       y, fy, wt, W1, b1, W2, b2, W3, b3, nbr, out, npts);
}

// Round 3
// 210.058 us; speedup vs baseline: 17.8866x; 1.2726x over previous
//
#include <hip/hip_runtime.h>
#include <hip/hip_bf16.h>
#include <math.h>

// IntegralTransform via bf16 MFMA (16x16x32). Persistent grid: 1024 blocks x
// 4 waves = 4096 waves, all resident; each wave loops over ~12 points
// (one point = 32 edges = 2 M=16 tiles). Weight B-fragments loaded ONCE per
// wave. Activations round-trip per-wave LDS bufB (h1 and h2), leaving the
// staged bufA (bf16 fy|y) intact so the epilogue scale reads LDS, not global.
// No __syncthreads: buffers are per-wave, same-wave DS ops are in order.

typedef __attribute__((ext_vector_type(8))) short short8;
typedef __attribute__((ext_vector_type(4))) float floatx4;

__device__ __forceinline__ unsigned short bf16rne(float f) {
    unsigned int u = __float_as_uint(f);
    u += 0x7fffu + ((u >> 16) & 1u);
    return (unsigned short)(u >> 16);
}
__device__ __forceinline__ unsigned int pk2(float a, float b) {
    union { __hip_bfloat162 h; unsigned int u; } cv;
    cv.h = __float22bfloat162_rn(make_float2(a, b));
    return cv.u;
}
__device__ __forceinline__ float bf16f(unsigned short u) {
    return __uint_as_float(((unsigned int)u) << 16);
}
// tanh-form gelu, 8 ops: x*(1 - 1/(exp2(c*x*(1+0.044715x^2)) + 1))
// c = 2*0.7978845608*log2(e) = 2.3022083
__device__ __forceinline__ float gelu_fast(float x) {
    float u = x * fmaf(0.044715f * x, x, 1.0f);
    float e = __expf(1.5957691f * u);   // exp(2z); compiles to mul+v_exp_f32
    float r = __builtin_amdgcn_rcpf(e + 1.0f);
    return fmaf(-x, r, x);
}

#define MFMA16(a, b, c) __builtin_amdgcn_mfma_f32_16x16x32_bf16(a, b, c, 0, 0, 0)

__global__ __launch_bounds__(256, 4) void it_mfma(
    const float* __restrict__ y, const float* __restrict__ fy,
    const float* __restrict__ wts,
    const float* __restrict__ W1, const float* __restrict__ b1,
    const float* __restrict__ W2, const float* __restrict__ b2,
    const float* __restrict__ W3, const float* __restrict__ b3,
    const int* __restrict__ nbr,
    float* __restrict__ out, int npts)
{
    __shared__ unsigned short lds[4][2][32][72];   // 36864 B
    __shared__ float warr[4][32];                  // per-row wts[j]

    const int lane = threadIdx.x & 63;
    const int wv   = threadIdx.x >> 6;
    const int quad = lane >> 4;
    const int c16  = lane & 15;
    const int wgid   = blockIdx.x * 4 + wv;
    const int nwaves = gridDim.x * 4;

    // ---- weight fragments (bf16, B-layout: k = 32*kb + 8*quad + j, n = 16*nb + c16)
    // k-permutation: k'<32 -> W1 row 6+k' (fy block); 32..37 -> rows 0..5; else 0
    short8 w1f[2][4], w2f[2][4], w3f[2][2];
    #pragma unroll
    for (int kb = 0; kb < 2; ++kb)
        #pragma unroll
        for (int nb = 0; nb < 4; ++nb)
            #pragma unroll
            for (int j = 0; j < 8; ++j) {
                int kp = kb * 32 + quad * 8 + j;
                int n  = nb * 16 + c16;
                int r  = (kp < 32) ? (6 + kp) : (kp < 38 ? kp - 32 : -1);
                float v = (r >= 0) ? W1[r * 64 + n] : 0.f;
                w1f[kb][nb][j] = (short)bf16rne(v);
            }
    #pragma unroll
    for (int kb = 0; kb < 2; ++kb)
        #pragma unroll
        for (int nb = 0; nb < 4; ++nb)
            #pragma unroll
            for (int j = 0; j < 8; ++j) {
                int k = kb * 32 + quad * 8 + j;
                w2f[kb][nb][j] = (short)bf16rne(W2[k * 64 + nb * 16 + c16]);
            }
    #pragma unroll
    for (int kb = 0; kb < 2; ++kb)
        #pragma unroll
        for (int nb = 0; nb < 2; ++nb)
            #pragma unroll
            for (int j = 0; j < 8; ++j) {
                int k = kb * 32 + quad * 8 + j;
                w3f[kb][nb][j] = (short)bf16rne(W3[k * 32 + nb * 16 + c16]);
            }
    float b1v[4], b2v[4], b3v[2];
    #pragma unroll
    for (int nb = 0; nb < 4; ++nb) { b1v[nb] = b1[nb * 16 + c16]; b2v[nb] = b2[nb * 16 + c16]; }
    b3v[0] = b3[c16]; b3v[1] = b3[16 + c16];

    unsigned short (*bufA)[72] = lds[wv][0];
    unsigned short (*bufB)[72] = lds[wv][1];

    // one-time zero of bufA cols 40..63 (stage only rewrites cols 0..39)
    if (lane < 32) {
        uint4 z = make_uint4(0u, 0u, 0u, 0u);
        *(uint4*)&bufA[lane][40] = z;
        *(uint4*)&bufA[lane][48] = z;
        *(uint4*)&bufA[lane][56] = z;
    }

    const floatx4 fz = {0.f, 0.f, 0.f, 0.f};

    for (int p = wgid; p < npts; p += nwaves) {
        const int pu = __builtin_amdgcn_readfirstlane(p);
        // ---- stage: 2 lanes per edge-row pack fy halves; lanes<32 pack y+w ----
        const int j32 = nbr[pu * 32 + (lane & 31)];
        const int row = lane >> 1;
        const int jr  = __shfl(j32, row, 64);
        {
            const int half = (lane & 1) << 4;          // cols 0..15 or 16..31
            const float4* fp = (const float4*)(fy + (long)jr * 32 + half);
            float4 v0 = fp[0], v1 = fp[1], v2 = fp[2], v3 = fp[3];
            *(uint4*)&bufA[row][half] =
                make_uint4(pk2(v0.x, v0.y), pk2(v0.z, v0.w), pk2(v1.x, v1.y), pk2(v1.z, v1.w));
            *(uint4*)&bufA[row][half + 8] =
                make_uint4(pk2(v2.x, v2.y), pk2(v2.z, v2.w), pk2(v3.x, v3.y), pk2(v3.z, v3.w));
        }
        if (lane < 32) {
            float yj0 = y[3 * j32], yj1 = y[3 * j32 + 1], yj2 = y[3 * j32 + 2];
            float yi0 = y[3 * pu], yi1 = y[3 * pu + 1], yi2 = y[3 * pu + 2];
            *(uint4*)&bufA[lane][32] =
                make_uint4(pk2(yj0, yj1), pk2(yj2, yi0), pk2(yi1, yi2), 0u);
            warr[wv][lane] = wts[j32];
        }

        float colsum0 = 0.f, colsum1 = 0.f;

        #pragma unroll
        for (int t = 0; t < 2; ++t) {
            const int arow = t * 16 + c16;
            // ---- layer 1: A from bufA (staged input), h1 -> bufB ----
            short8 a0 = *(const short8*)&bufA[arow][quad * 8];
            short8 a1 = *(const short8*)&bufA[arow][32 + quad * 8];
            floatx4 acc[4];
            #pragma unroll
            for (int nb = 0; nb < 4; ++nb) {
                acc[nb] = MFMA16(a0, w1f[0][nb], fz);
                acc[nb] = MFMA16(a1, w1f[1][nb], acc[nb]);
            }
            #pragma unroll
            for (int r = 0; r < 4; ++r) {
                float g0 = gelu_fast(acc[0][r] + b1v[0]);
                float g1 = gelu_fast(acc[1][r] + b1v[1]);
                float g2 = gelu_fast(acc[2][r] + b1v[2]);
                float g3 = gelu_fast(acc[3][r] + b1v[3]);
                unsigned int p01 = pk2(g0, g1), p23 = pk2(g2, g3);
                int orow = t * 16 + quad * 4 + r;
                bufB[orow][c16]      = (unsigned short)p01;
                bufB[orow][16 + c16] = (unsigned short)(p01 >> 16);
                bufB[orow][32 + c16] = (unsigned short)p23;
                bufB[orow][48 + c16] = (unsigned short)(p23 >> 16);
            }
            // ---- layer 2: A from bufB, h2 -> bufB (reads precede writes in-order) ----
            short8 h0 = *(const short8*)&bufB[arow][quad * 8];
            short8 h1 = *(const short8*)&bufB[arow][32 + quad * 8];
            #pragma unroll
            for (int nb = 0; nb < 4; ++nb) {
                acc[nb] = MFMA16(h0, w2f[0][nb], fz);
                acc[nb] = MFMA16(h1, w2f[1][nb], acc[nb]);
            }
            #pragma unroll
            for (int r = 0; r < 4; ++r) {
                float g0 = gelu_fast(acc[0][r] + b2v[0]);
                float g1 = gelu_fast(acc[1][r] + b2v[1]);
                float g2 = gelu_fast(acc[2][r] + b2v[2]);
                float g3 = gelu_fast(acc[3][r] + b2v[3]);
                unsigned int p01 = pk2(g0, g1), p23 = pk2(g2, g3);
                int orow = t * 16 + quad * 4 + r;
                bufB[orow][c16]      = (unsigned short)p01;
                bufB[orow][16 + c16] = (unsigned short)(p01 >> 16);
                bufB[orow][32 + c16] = (unsigned short)p23;
                bufB[orow][48 + c16] = (unsigned short)(p23 >> 16);
            }
            // ---- layer 3 ----
            short8 g0 = *(const short8*)&bufB[arow][quad * 8];
            short8 g1 = *(const short8*)&bufB[arow][32 + quad * 8];
            floatx4 o[2];
            #pragma unroll
            for (int nb = 0; nb < 2; ++nb) {
                o[nb] = MFMA16(g0, w3f[0][nb], fz);
                o[nb] = MFMA16(g1, w3f[1][nb], o[nb]);
            }
            // ---- epilogue: (o + b3) * fy[j] * w[j] from LDS, accumulate rows ----
            #pragma unroll
            for (int r = 0; r < 4; ++r) {
                int orow = t * 16 + quad * 4 + r;
                float wr = warr[wv][orow];
                float f0 = bf16f(bufA[orow][c16]);
                float f1 = bf16f(bufA[orow][16 + c16]);
                colsum0 = fmaf((o[0][r] + b3v[0]) * f0, wr, colsum0);
                colsum1 = fmaf((o[1][r] + b3v[1]) * f1, wr, colsum1);
            }
        }

        // reduce across quads (rows) and store one point [32 ch]
        colsum0 += __shfl_xor(colsum0, 16, 64);
        colsum0 += __shfl_xor(colsum0, 32, 64);
        colsum1 += __shfl_xor(colsum1, 16, 64);
        colsum1 += __shfl_xor(colsum1, 32, 64);
        if (lane < 32)
            out[pu * 32 + lane] = (lane < 16) ? colsum0 : colsum1;
    }
}

extern "C" void kernel_launch(void* const* d_in, const int* in_sizes, int n_in,
                              void* d_out, int out_size, void* d_ws, size_t ws_size,
                              hipStream_t stream) {
    const float* y  = (const float*)d_in[0];
    const float* fy = (const float*)d_in[1];
    const float* wt = (const float*)d_in[2];
    const float* W1 = (const float*)d_in[3];
    const float* b1 = (const float*)d_in[4];
    const float* W2 = (const float*)d_in[5];
    const float* b2 = (const float*)d_in[6];
    const float* W3 = (const float*)d_in[7];
    const float* b3 = (const float*)d_in[8];
    const int* nbr  = (const int*)d_in[9];
    const int E = in_sizes[9];
    const int npts = E >> 5;              // K = 32 fixed
    float* out = (float*)d_out;

    // persistent: 1024 blocks x 4 waves = 4096 waves, fully resident
    // (LDS 37.4 KB -> 4 blocks/CU; VGPR <=128 -> 4 waves/SIMD)
    hipLaunchKernelGGL(it_mfma, dim3(1024), dim3(256), 0, stream,
                       y, fy, wt, W1, b1, W2, b2, W3, b3, nbr, out, npts);
}